// Round 14
// baseline (177.136 us; speedup 1.0000x reference)
//
#include <hip/hip_runtime.h>
#include <hip/hip_bf16.h>

typedef __bf16 bf16_t;
typedef __bf16 bf16x8 __attribute__((ext_vector_type(8)));
typedef float  f32x4  __attribute__((ext_vector_type(4)));

#define DEVFN static __device__ __forceinline__

constexpr int TOK   = 32 * 512;        // 16384 tokens
constexpr int W_OFF = TOK * 128;       // weights offset (floats) in d_out

// d_ws byte offsets
constexpr size_t WS_A_VW2 = 0;                                  // 1MB (bf16, XOR-swizzled rows)
constexpr size_t WS_A_WG2 = (size_t)1 << 20;                    // 1MB (bf16, XOR-swizzled rows)
constexpr size_t WS_BG2   = (size_t)2 << 20;                    // 16KB f32 [32][128]
constexpr size_t WS_A_FW2 = ((size_t)2 << 20) + (64u  << 10);   // 32KB (swizzled, k1)
constexpr size_t WS_A_WG1 = ((size_t)2 << 20) + (128u << 10);   // 32KB (swizzled, k1)
constexpr size_t WS_BG1   = ((size_t)2 << 20) + (192u << 10);   // 512B f32 [128]
constexpr size_t WS_A_FW1 = ((size_t)2 << 20) + (224u << 10);   // 8KB  (bf16, plain)
constexpr size_t WS_A_FSW = ((size_t)2 << 20) + (256u << 10);   // 8KB  (bf16, plain)
constexpr size_t WS_PART  = (size_t)3 << 20;                    // partial selected buffers
constexpr size_t PART_SZ  = (size_t)TOK * 128 * 4;              // 8.39MB each

DEVFN float eluf(float z)  { return z > 0.0f ? z : (__expf(z) - 1.0f); }
DEVFN float sigmf(float z) { return __builtin_amdgcn_rcpf(1.0f + __expf(-z)); }
DEVFN unsigned short f2bfu(float f){ bf16_t h = (bf16_t)f; return __builtin_bit_cast(unsigned short, h); }

DEVFN uint4 pack8(f32x4 a, f32x4 b){
  uint4 r;
  r.x = (unsigned)f2bfu(a[0]) | ((unsigned)f2bfu(a[1]) << 16);
  r.y = (unsigned)f2bfu(a[2]) | ((unsigned)f2bfu(a[3]) << 16);
  r.z = (unsigned)f2bfu(b[0]) | ((unsigned)f2bfu(b[1]) << 16);
  r.w = (unsigned)f2bfu(b[2]) | ((unsigned)f2bfu(b[3]) << 16);
  return r;
}
DEVFN f32x4 mfma16(bf16x8 a, bf16x8 b, f32x4 c){
  return __builtin_amdgcn_mfma_f32_16x16x32_bf16(a, b, c, 0, 0, 0);
}
DEVFN bf16x8 asbf(uint4 u){ return __builtin_bit_cast(bf16x8, u); }

// ---------------------------------------------------------------------------
// K0 (R12-verbatim): fused gate matrices (Wg2 = vgw·vw2, Wg1 = fgw·fw2, fused
// biases), bf16 packing, slab XOR-swizzle (frag f of row r stored at f^(r&7)).
// ---------------------------------------------------------------------------
__global__ void k0_prep(const float* __restrict__ fw1, const float* __restrict__ fw2,
                        const float* __restrict__ fgw, const float* __restrict__ fgb,
                        const float* __restrict__ fb2, const float* __restrict__ fsw,
                        const float* __restrict__ vw2, const float* __restrict__ vgw,
                        const float* __restrict__ vgb, const float* __restrict__ vb2,
                        unsigned char* __restrict__ ws)
{
  const int b = blockIdx.x, tid = threadIdx.x;
  if (b < 256){
    const int v  = b >> 3;
    const int k2 = (b & 7) * 16 + (tid >> 4);
    const int h0 = (tid & 15) * 8;
    const float* gw = vgw + ((size_t)v * 128 + k2) * 128;
    const float* w2 = vw2 + (size_t)v * 128 * 128;
    f32x4 a0 = {0,0,0,0}, a1 = {0,0,0,0};
    for (int k = 0; k < 128; ++k){
      float a = gw[k];
      f32x4 u = *(const f32x4*)(w2 + k*128 + h0);
      f32x4 w = *(const f32x4*)(w2 + k*128 + h0 + 4);
      #pragma unroll
      for (int e = 0; e < 4; ++e){ a0[e] = fmaf(a, u[e], a0[e]); a1[e] = fmaf(a, w[e], a1[e]); }
    }
    unsigned blk = (unsigned)(h0 >> 3) ^ (unsigned)(k2 & 7);
    *(uint4*)(ws + WS_A_WG2 + (size_t)v*32768 + (size_t)k2*256 + blk*16) = pack8(a0, a1);
    if ((b & 7) == 0 && tid < 128){
      const float* gr = vgw + ((size_t)v*128 + tid) * 128;
      const float* vb = vb2 + v*128;
      float s = vgb[v*128 + tid];
      for (int k = 0; k < 128; ++k) s = fmaf(gr[k], vb[k], s);
      ((float*)(ws + WS_BG2))[v*128 + tid] = s;
    }
  } else if (b < 288){
    const int v = b - 256;
    const int k = tid >> 1, hh = (tid & 1) * 64;
    const float* src = vw2 + ((size_t)v*128 + k) * 128;
    #pragma unroll
    for (int i = 0; i < 8; ++i){
      int h0 = hh + i*8;
      f32x4 a = *(const f32x4*)(src + h0);
      f32x4 c = *(const f32x4*)(src + h0 + 4);
      unsigned blk = (unsigned)(h0 >> 3) ^ (unsigned)(k & 7);
      *(uint4*)(ws + WS_A_VW2 + (size_t)v*32768 + (size_t)k*256 + blk*16) = pack8(a, c);
    }
  } else if (b < 296){
    const int k2 = (b - 288) * 16 + (tid >> 4);
    const int h0 = (tid & 15) * 8;
    const float* gw = fgw + (size_t)k2 * 128;
    f32x4 a0 = {0,0,0,0}, a1 = {0,0,0,0};
    for (int k = 0; k < 128; ++k){
      float a = gw[k];
      f32x4 u = *(const f32x4*)(fw2 + k*128 + h0);
      f32x4 w = *(const f32x4*)(fw2 + k*128 + h0 + 4);
      #pragma unroll
      for (int e = 0; e < 4; ++e){ a0[e] = fmaf(a, u[e], a0[e]); a1[e] = fmaf(a, w[e], a1[e]); }
    }
    unsigned blk = (unsigned)(h0 >> 3) ^ (unsigned)(k2 & 7);
    *(uint4*)(ws + WS_A_WG1 + (size_t)k2*256 + blk*16) = pack8(a0, a1);
    if (b == 288 && tid < 128){
      const float* gr = fgw + (size_t)tid * 128;
      float s = fgb[tid];
      for (int k = 0; k < 128; ++k) s = fmaf(gr[k], fb2[k], s);
      ((float*)(ws + WS_BG1))[tid] = s;
    }
  } else if (b == 296){
    const int k = tid >> 1, hh = (tid & 1) * 64;
    const float* src = fw2 + (size_t)k * 128;
    #pragma unroll
    for (int i = 0; i < 8; ++i){
      int h0 = hh + i*8;
      f32x4 a = *(const f32x4*)(src + h0);
      f32x4 c = *(const f32x4*)(src + h0 + 4);
      unsigned blk = (unsigned)(h0 >> 3) ^ (unsigned)(k & 7);
      *(uint4*)(ws + WS_A_FW2 + (size_t)k*256 + blk*16) = pack8(a, c);
    }
  } else if (b == 297){
    const int k = tid >> 1, v0 = (tid & 1) * 16;
    #pragma unroll
    for (int i = 0; i < 2; ++i){
      f32x4 a  = *(const f32x4*)(fw1 + k*32 + v0 + i*8);
      f32x4 c  = *(const f32x4*)(fw1 + k*32 + v0 + i*8 + 4);
      *(uint4*)(ws + WS_A_FW1 + (size_t)k*64 + (size_t)v0*2 + i*16) = pack8(a, c);
      f32x4 a2 = *(const f32x4*)(fsw + k*32 + v0 + i*8);
      f32x4 c2 = *(const f32x4*)(fsw + k*32 + v0 + i*8 + 4);
      *(uint4*)(ws + WS_A_FSW + (size_t)k*64 + (size_t)v0*2 + i*16) = pack8(a2, c2);
    }
  }
}

// ---------------------------------------------------------------------------
// K1 (R12-verbatim): flattened GRN -> softmax weights (d_out[W_OFF..]).
// ---------------------------------------------------------------------------
__global__ __launch_bounds__(256) void k1_flat(
  const float* __restrict__ x,   const float* __restrict__ fb1,
  const float* __restrict__ fb2, const float* __restrict__ fsb,
  const float* __restrict__ flnw,const float* __restrict__ flnb,
  const unsigned char* __restrict__ ws, float* __restrict__ out)
{
  __shared__ __align__(16) unsigned char ldsW[65536];
  __shared__ __align__(16) unsigned char ldsH[4][4096];
  const int tid = threadIdx.x;
  const int wid = tid >> 6, lane = tid & 63;
  const int tl = lane & 15, q = lane >> 4;
  const int t0 = blockIdx.x * 64;
  const int tw = t0 + wid * 16 + tl;

  { // stage fw2' and wg1' into LDS
    const uint4* s1 = (const uint4*)(ws + WS_A_FW2);
    const uint4* s2 = (const uint4*)(ws + WS_A_WG1);
    uint4* d1 = (uint4*)ldsW;
    uint4* d2 = (uint4*)(ldsW + 32768);
    #pragma unroll
    for (int i = 0; i < 8; ++i){ d1[tid + i*256] = s1[tid + i*256]; d2[tid + i*256] = s2[tid + i*256]; }
  }
  bf16x8 xf;
  {
    f32x4 a = *(const f32x4*)(x + (size_t)tw*32 + q*8);
    f32x4 c = *(const f32x4*)(x + (size_t)tw*32 + q*8 + 4);
    #pragma unroll
    for (int e = 0; e < 4; ++e){ xf[e] = (bf16_t)a[e]; xf[e+4] = (bf16_t)c[e]; }
  }
  __syncthreads();

  const unsigned swzt = (unsigned)(tl & 7) << 4;
  #pragma unroll
  for (int mt = 0; mt < 8; ++mt){
    const int row = mt*16 + tl;
    uint4 araw = *(const uint4*)(ws + WS_A_FW1 + (size_t)row*64 + q*16);
    f32x4 acc = *(const f32x4*)(fb1 + mt*16 + q*4);
    acc = mfma16(asbf(araw), xf, acc);
    ushort4 hb;
    hb.x = f2bfu(eluf(acc[0])); hb.y = f2bfu(eluf(acc[1]));
    hb.z = f2bfu(eluf(acc[2])); hb.w = f2bfu(eluf(acc[3]));
    *(ushort4*)(ldsH[wid] + (unsigned)tl*256 + (((unsigned)(mt*32 + q*8)) ^ swzt)) = hb;
  }
  bf16x8 h1f[4];
  #pragma unroll
  for (int kb = 0; kb < 4; ++kb)
    h1f[kb] = asbf(*(const uint4*)(ldsH[wid] + (unsigned)tl*256 + (((unsigned)(kb*64 + q*16)) ^ swzt)));

  f32x4 wo[8];
  const float* bg1p = (const float*)(ws + WS_BG1);
  #pragma unroll
  for (int mt = 0; mt < 8; ++mt){
    const int row = mt*16 + tl;
    const uint4* aw = (const uint4*)(ldsW + (size_t)row*256);
    const uint4* ag = (const uint4*)(ldsW + 32768 + (size_t)row*256);
    const unsigned rsw = (unsigned)(row & 7);
    f32x4 h2 = *(const f32x4*)(fb2 + mt*16 + q*4);
    f32x4 gp = *(const f32x4*)(bg1p + mt*16 + q*4);
    #pragma unroll
    for (int kb = 0; kb < 4; ++kb){
      unsigned blk = (unsigned)(kb*4 + q) ^ rsw;
      h2 = mfma16(asbf(aw[blk]), h1f[kb], h2);
      gp = mfma16(asbf(ag[blk]), h1f[kb], gp);
    }
    uint4 asr = *(const uint4*)(ws + WS_A_FSW + (size_t)row*64 + q*16);
    f32x4 sk = *(const f32x4*)(fsb + mt*16 + q*4);
    sk = mfma16(asbf(asr), xf, sk);
    #pragma unroll
    for (int r = 0; r < 4; ++r){
      float g = sigmf(gp[r]);
      wo[mt][r] = sk[r] + g * (h2[r] - sk[r]);
    }
  }
  float sm = 0.f, sq = 0.f;
  #pragma unroll
  for (int mt = 0; mt < 8; ++mt)
  #pragma unroll
  for (int r = 0; r < 4; ++r){ float p = wo[mt][r]; sm += p; sq = fmaf(p, p, sq); }
  sm += __shfl_xor(sm, 16); sm += __shfl_xor(sm, 32);
  sq += __shfl_xor(sq, 16); sq += __shfl_xor(sq, 32);
  const float mean = sm * (1.f/128.f);
  const float var  = sq * (1.f/128.f) - mean*mean;
  const float rs   = __builtin_amdgcn_rsqf(var + 1e-5f);
  float wv[8];
  #pragma unroll
  for (int mt = 0; mt < 2; ++mt){
    f32x4 lw = *(const f32x4*)(flnw + mt*16 + q*4);
    f32x4 lb = *(const f32x4*)(flnb + mt*16 + q*4);
    #pragma unroll
    for (int r = 0; r < 4; ++r) wv[mt*4+r] = (wo[mt][r] - mean) * rs * lw[r] + lb[r];
  }
  float mx = wv[0];
  #pragma unroll
  for (int j = 1; j < 8; ++j) mx = fmaxf(mx, wv[j]);
  mx = fmaxf(mx, __shfl_xor(mx, 16)); mx = fmaxf(mx, __shfl_xor(mx, 32));
  float se = 0.f;
  #pragma unroll
  for (int j = 0; j < 8; ++j){ wv[j] = __expf(wv[j] - mx); se += wv[j]; }
  se += __shfl_xor(se, 16); se += __shfl_xor(se, 32);
  const float inv = __builtin_amdgcn_rcpf(se);
  #pragma unroll
  for (int mt = 0; mt < 2; ++mt)
  #pragma unroll
  for (int r = 0; r < 4; ++r)
    out[(size_t)W_OFF + (size_t)tw*32 + mt*16 + q*4 + r] = wv[mt*4+r] * inv;
}

// ---------------------------------------------------------------------------
// K2 (R14): R12 shell + nt=2. 256 threads = 4 waves x 32 tokens (each slab
// fragment read feeds TWO token-group MFMAs -> LDS-pipe traffic per token
// halved vs R12); VPG=8; grid = 128 chunks x 4 groups = 512 blocks -> 2
// blocks/CU -> 8 waves/CU with co-resident-block barrier overlap. Single
// 64KB slab, R11/R12-proven sync (stage -> barrier -> compute -> barrier).
// (256,1) -> 256-VGPR cap (R8 precedent), demand ~225, no spill expected.
// nt=2 math R2/R6/R13-proven. Group nvg-1 -> out; others -> partials (k3).
// ---------------------------------------------------------------------------
__global__ __launch_bounds__(256, 1) void k2_main(
  const float* __restrict__ x,   const float* __restrict__ vw1,
  const float* __restrict__ vb1, const float* __restrict__ vb2,
  const float* __restrict__ vsw, const float* __restrict__ vsb,
  const float* __restrict__ vlnw,const float* __restrict__ vlnb,
  const unsigned char* __restrict__ ws, float* __restrict__ out,
  float* __restrict__ part, int nvg)
{
  __shared__ __align__(16) uint4 slab[4096];   // [A 2048 | G 2048] = 64KB
  const int tid = threadIdx.x;                 // 0..255
  const int wid = tid >> 6, lane = tid & 63;   // 4 waves
  const int tl = lane & 15, q = lane >> 4;
  const int bid = blockIdx.x;
  const int c   = bid & 127;                   // token chunk (128 x 128 tokens)
  const int g   = bid >> 7;                    // v-group
  const int VPG = 32 / nvg;
  const int vbase = g * VPG;
  const int t0 = ((c & 7) * 16 + (c >> 3)) * 128;   // XCD-clustered, bijective
  const int ta = t0 + wid * 32 + tl, tb = ta + 16;
  const float* bg2p = (const float*)(ws + WS_BG2);
  float* __restrict__ dst = (g == nvg - 1) ? out : (part + (size_t)g * TOK * 128);

  { // stage slab for v = vbase
    const uint4* sa = (const uint4*)(ws + WS_A_VW2 + (size_t)vbase*32768);
    const uint4* sg = (const uint4*)(ws + WS_A_WG2 + (size_t)vbase*32768);
    #pragma unroll
    for (int i = 0; i < 8; ++i) slab[tid + i*256] = sa[tid + i*256];
    #pragma unroll
    for (int i = 0; i < 8; ++i) slab[2048 + tid + i*256] = sg[tid + i*256];
  }
  __syncthreads();

  f32x4 sel[2][8];
  #pragma unroll
  for (int mt = 0; mt < 8; ++mt){ sel[0][mt] = (f32x4){0,0,0,0}; sel[1][mt] = (f32x4){0,0,0,0}; }

  for (int vi = 0; vi < VPG; ++vi){
    const int v = vbase + vi;
    const float xv0 = x[(size_t)ta*32 + v];
    const float xv1 = x[(size_t)tb*32 + v];
    const float wt0 = out[(size_t)W_OFF + (size_t)ta*32 + v];
    const float wt1 = out[(size_t)W_OFF + (size_t)tb*32 + v];

    // B-fragments: hv1 = elu(x*vw1 + vb1), elem e <-> h = kb*32 + 8q + e
    bf16x8 bf0[4], bf1[4];
    #pragma unroll
    for (int kb = 0; kb < 4; ++kb){
      const float* wp = vw1 + v*128 + kb*32 + q*8;
      const float* bp = vb1 + v*128 + kb*32 + q*8;
      f32x4 w0v = *(const f32x4*)wp, w1v = *(const f32x4*)(wp + 4);
      f32x4 b0v = *(const f32x4*)bp, b1v = *(const f32x4*)(bp + 4);
      bf16x8 f0, f1;
      #pragma unroll
      for (int e = 0; e < 4; ++e){
        f0[e]   = (bf16_t)eluf(fmaf(xv0, w0v[e], b0v[e]));
        f0[e+4] = (bf16_t)eluf(fmaf(xv0, w1v[e], b1v[e]));
        f1[e]   = (bf16_t)eluf(fmaf(xv1, w0v[e], b0v[e]));
        f1[e+4] = (bf16_t)eluf(fmaf(xv1, w1v[e], b1v[e]));
      }
      bf0[kb] = f0; bf1[kb] = f1;
    }

    // fused GEMMs from LDS slab — each fragment read feeds both token groups
    f32x4 pre[8][2];
    #pragma unroll
    for (int mt = 0; mt < 8; ++mt){
      const int row = mt*16 + tl;
      const uint4* arow = slab + row*16;
      const uint4* grow = slab + 2048 + row*16;
      const unsigned rsw = (unsigned)(row & 7);
      f32x4 bini = *(const f32x4*)(vb2 + v*128 + mt*16 + q*4);
      f32x4 gini = *(const f32x4*)(bg2p + v*128 + mt*16 + q*4);
      f32x4 h0 = bini, h1 = bini, g0 = gini, g1 = gini;
      #pragma unroll
      for (int kb = 0; kb < 4; ++kb){
        const unsigned blk = (unsigned)(kb*4 + q) ^ rsw;
        bf16x8 a  = asbf(arow[blk]);
        bf16x8 gg = asbf(grow[blk]);
        h0 = mfma16(a,  bf0[kb], h0);
        h1 = mfma16(a,  bf1[kb], h1);
        g0 = mfma16(gg, bf0[kb], g0);
        g1 = mfma16(gg, bf1[kb], g1);
      }
      f32x4 sw_ = *(const f32x4*)(vsw + v*128 + mt*16 + q*4);
      f32x4 sb_ = *(const f32x4*)(vsb + v*128 + mt*16 + q*4);
      #pragma unroll
      for (int r = 0; r < 4; ++r){
        float sk0 = fmaf(xv0, sw_[r], sb_[r]);
        float sk1 = fmaf(xv1, sw_[r], sb_[r]);
        pre[mt][0][r] = sk0 + sigmf(g0[r]) * (h0[r] - sk0);
        pre[mt][1][r] = sk1 + sigmf(g1[r]) * (h1[r] - sk1);
      }
    }

    // LayerNorm + weighted select accumulation (both token groups)
    #pragma unroll
    for (int nt = 0; nt < 2; ++nt){
      const float wt = nt ? wt1 : wt0;
      float sm = 0.f, sq = 0.f;
      #pragma unroll
      for (int mt = 0; mt < 8; ++mt)
      #pragma unroll
      for (int r = 0; r < 4; ++r){ float p = pre[mt][nt][r]; sm += p; sq = fmaf(p, p, sq); }
      sm += __shfl_xor(sm, 16); sm += __shfl_xor(sm, 32);
      sq += __shfl_xor(sq, 16); sq += __shfl_xor(sq, 32);
      const float mean = sm * (1.f/128.f);
      const float var  = sq * (1.f/128.f) - mean*mean;
      const float rsq  = __builtin_amdgcn_rsqf(var + 1e-5f);
      const float c1   = wt * rsq;
      #pragma unroll
      for (int mt = 0; mt < 8; ++mt){
        f32x4 lw = *(const f32x4*)(vlnw + v*128 + mt*16 + q*4);
        f32x4 lb = *(const f32x4*)(vlnb + v*128 + mt*16 + q*4);
        #pragma unroll
        for (int r = 0; r < 4; ++r)
          sel[nt][mt][r] = fmaf((pre[mt][nt][r] - mean) * lw[r], c1,
                                fmaf(wt, lb[r], sel[nt][mt][r]));
      }
    }

    __syncthreads();                       // all waves done READING slab(v)
    if (vi + 1 < VPG){                     // restage slab(v+1), then barrier
      const uint4* sa = (const uint4*)(ws + WS_A_VW2 + (size_t)(v+1)*32768);
      const uint4* sg = (const uint4*)(ws + WS_A_WG2 + (size_t)(v+1)*32768);
      #pragma unroll
      for (int i = 0; i < 8; ++i) slab[tid + i*256] = sa[tid + i*256];
      #pragma unroll
      for (int i = 0; i < 8; ++i) slab[2048 + tid + i*256] = sg[tid + i*256];
      __syncthreads();
    }
  }

  // tail: direct stores (per mt: 4 q-lanes form one 64B segment per token)
  #pragma unroll
  for (int mt = 0; mt < 8; ++mt){
    *(f32x4*)(dst + (size_t)ta*128 + mt*16 + q*4) = sel[0][mt];
    *(f32x4*)(dst + (size_t)tb*128 + mt*16 + q*4) = sel[1][mt];
  }
}

// ---------------------------------------------------------------------------
// K3: out += sum of partials (deterministic fixed order)
// ---------------------------------------------------------------------------
__global__ __launch_bounds__(256) void k3_reduce(float* __restrict__ out,
                                                 const float* __restrict__ part,
                                                 int nparts)
{
  const size_t idx = (size_t)blockIdx.x * 256 + threadIdx.x;
  f32x4 s = ((const f32x4*)out)[idx];
  for (int g = 0; g < nparts; ++g){
    f32x4 p = ((const f32x4*)part)[(size_t)g * TOK * 32 + idx];
    #pragma unroll
    for (int r = 0; r < 4; ++r) s[r] += p[r];
  }
  ((f32x4*)out)[idx] = s;
}

// ---------------------------------------------------------------------------
extern "C" void kernel_launch(void* const* d_in, const int* in_sizes, int n_in,
                              void* d_out, int out_size, void* d_ws, size_t ws_size,
                              hipStream_t stream)
{
  (void)in_sizes; (void)n_in; (void)out_size;
  const float* x    = (const float*)d_in[0];
  const float* fw1  = (const float*)d_in[1];
  const float* fb1  = (const float*)d_in[2];
  const float* fw2  = (const float*)d_in[3];
  const float* fb2  = (const float*)d_in[4];
  const float* fgw  = (const float*)d_in[5];
  const float* fgb  = (const float*)d_in[6];
  const float* fsw  = (const float*)d_in[7];
  const float* fsb  = (const float*)d_in[8];
  const float* flnw = (const float*)d_in[9];
  const float* flnb = (const float*)d_in[10];
  const float* vw1  = (const float*)d_in[11];
  const float* vb1  = (const float*)d_in[12];
  const float* vw2  = (const float*)d_in[13];
  const float* vb2  = (const float*)d_in[14];
  const float* vgw  = (const float*)d_in[15];
  const float* vgb  = (const float*)d_in[16];
  const float* vsw  = (const float*)d_in[17];
  const float* vsb  = (const float*)d_in[18];
  const float* vlnw = (const float*)d_in[19];
  const float* vlnb = (const float*)d_in[20];
  float* out = (float*)d_out;
  unsigned char* ws = (unsigned char*)d_ws;
  float* part = (float*)(ws + WS_PART);

  k0_prep<<<298, 256, 0, stream>>>(fw1, fw2, fgw, fgb, fb2, fsw, vw2, vgw, vgb, vb2, ws);
  k1_flat<<<256, 256, 0, stream>>>(x, fb1, fb2, fsb, flnw, flnb, ws, out);

  if (ws_size >= WS_PART + 3 * PART_SZ){
    // 4 v-groups of 8 vars: grid 512 -> 2 blocks/CU, 8 waves/CU
    k2_main<<<512, 256, 0, stream>>>(x, vw1, vb1, vb2, vsw, vsb, vlnw, vlnb,
                                     ws, out, part, 4);
    k3_reduce<<<2048, 256, 0, stream>>>(out, part, 3);
  } else if (ws_size >= WS_PART + PART_SZ){
    // 2 v-groups of 16 vars: grid 256
    k2_main<<<256, 256, 0, stream>>>(x, vw1, vb1, vb2, vsw, vsb, vlnw, vlnb,
                                     ws, out, part, 2);
    k3_reduce<<<2048, 256, 0, stream>>>(out, part, 1);
  } else {
    // fallback: single group, all 32 vars, grid 128 (correctness-safe)
    k2_main<<<128, 256, 0, stream>>>(x, vw1, vb1, vb2, vsw, vsb, vlnw, vlnb,
                                     ws, out, part, 1);
  }
}

// Round 15
// 171.170 us; speedup vs baseline: 1.0349x; 1.0349x over previous
//
#include <hip/hip_runtime.h>
#include <hip/hip_bf16.h>

typedef __bf16 bf16_t;
typedef __bf16 bf16x8 __attribute__((ext_vector_type(8)));
typedef float  f32x4  __attribute__((ext_vector_type(4)));

#define DEVFN static __device__ __forceinline__

constexpr int TOK   = 32 * 512;        // 16384 tokens
constexpr int W_OFF = TOK * 128;       // weights offset (floats) in d_out

// d_ws byte offsets
constexpr size_t WS_A_VW2 = 0;                                  // 1MB (bf16, XOR-swizzled rows; LDS-staged)
constexpr size_t WS_A_WG2 = (size_t)1 << 20;                    // 1MB (bf16, FRAG-MAJOR coalesced; global-read)
constexpr size_t WS_BG2   = (size_t)2 << 20;                    // 16KB f32 [32][128]
constexpr size_t WS_A_FW2 = ((size_t)2 << 20) + (64u  << 10);   // 32KB (swizzled, k1)
constexpr size_t WS_A_WG1 = ((size_t)2 << 20) + (128u << 10);   // 32KB (swizzled, k1)
constexpr size_t WS_BG1   = ((size_t)2 << 20) + (192u << 10);   // 512B f32 [128]
constexpr size_t WS_A_FW1 = ((size_t)2 << 20) + (224u << 10);   // 8KB  (bf16, plain)
constexpr size_t WS_A_FSW = ((size_t)2 << 20) + (256u << 10);   // 8KB  (bf16, plain)
constexpr size_t WS_PART  = (size_t)3 << 20;                    // partial selected buffers
constexpr size_t PART_SZ  = (size_t)TOK * 128 * 4;              // 8.39MB each

DEVFN float eluf(float z)  { return z > 0.0f ? z : (__expf(z) - 1.0f); }
DEVFN float sigmf(float z) { return __builtin_amdgcn_rcpf(1.0f + __expf(-z)); }
DEVFN unsigned short f2bfu(float f){ bf16_t h = (bf16_t)f; return __builtin_bit_cast(unsigned short, h); }

DEVFN uint4 pack8(f32x4 a, f32x4 b){
  uint4 r;
  r.x = (unsigned)f2bfu(a[0]) | ((unsigned)f2bfu(a[1]) << 16);
  r.y = (unsigned)f2bfu(a[2]) | ((unsigned)f2bfu(a[3]) << 16);
  r.z = (unsigned)f2bfu(b[0]) | ((unsigned)f2bfu(b[1]) << 16);
  r.w = (unsigned)f2bfu(b[2]) | ((unsigned)f2bfu(b[3]) << 16);
  return r;
}
DEVFN f32x4 mfma16(bf16x8 a, bf16x8 b, f32x4 c){
  return __builtin_amdgcn_mfma_f32_16x16x32_bf16(a, b, c, 0, 0, 0);
}
DEVFN bf16x8 asbf(uint4 u){ return __builtin_bit_cast(bf16x8, u); }

// ---------------------------------------------------------------------------
// K0: fused gate matrices + bf16 packing. VW2 slab: XOR-swizzled rows
// (R12-verbatim, staged to LDS by k2). WG2 slab: NEW frag-major coalesced
// layout [v][(mt*4+kb)*64 + q*16 + tl] so k2's global g-frag reads are fully
// coalesced 1KB/instr. Same (lane,elem)->(row,k) mapping -> identical math.
// ---------------------------------------------------------------------------
__global__ void k0_prep(const float* __restrict__ fw1, const float* __restrict__ fw2,
                        const float* __restrict__ fgw, const float* __restrict__ fgb,
                        const float* __restrict__ fb2, const float* __restrict__ fsw,
                        const float* __restrict__ vw2, const float* __restrict__ vgw,
                        const float* __restrict__ vgb, const float* __restrict__ vb2,
                        unsigned char* __restrict__ ws)
{
  const int b = blockIdx.x, tid = threadIdx.x;
  if (b < 256){
    const int v  = b >> 3;
    const int k2 = (b & 7) * 16 + (tid >> 4);
    const int h0 = (tid & 15) * 8;
    const float* gw = vgw + ((size_t)v * 128 + k2) * 128;
    const float* w2 = vw2 + (size_t)v * 128 * 128;
    f32x4 a0 = {0,0,0,0}, a1 = {0,0,0,0};
    for (int k = 0; k < 128; ++k){
      float a = gw[k];
      f32x4 u = *(const f32x4*)(w2 + k*128 + h0);
      f32x4 w = *(const f32x4*)(w2 + k*128 + h0 + 4);
      #pragma unroll
      for (int e = 0; e < 4; ++e){ a0[e] = fmaf(a, u[e], a0[e]); a1[e] = fmaf(a, w[e], a1[e]); }
    }
    // frag-major: row k2 -> (mt=k2>>4, tl=k2&15); cols h0.. -> (kb=h0>>5, q=(h0>>3)&3)
    const int mt = k2 >> 4, tl = k2 & 15;
    const int kb = h0 >> 5, qq = (h0 >> 3) & 3;
    *(uint4*)(ws + WS_A_WG2 + (size_t)v*32768 +
              (size_t)(((mt*4 + kb)*64) + qq*16 + tl)*16) = pack8(a0, a1);
    if ((b & 7) == 0 && tid < 128){
      const float* gr = vgw + ((size_t)v*128 + tid) * 128;
      const float* vb = vb2 + v*128;
      float s = vgb[v*128 + tid];
      for (int k = 0; k < 128; ++k) s = fmaf(gr[k], vb[k], s);
      ((float*)(ws + WS_BG2))[v*128 + tid] = s;
    }
  } else if (b < 288){
    // vw2 -> bf16 XOR-swizzled rows (R12-verbatim)
    const int v = b - 256;
    const int k = tid >> 1, hh = (tid & 1) * 64;
    const float* src = vw2 + ((size_t)v*128 + k) * 128;
    #pragma unroll
    for (int i = 0; i < 8; ++i){
      int h0 = hh + i*8;
      f32x4 a = *(const f32x4*)(src + h0);
      f32x4 c = *(const f32x4*)(src + h0 + 4);
      unsigned blk = (unsigned)(h0 >> 3) ^ (unsigned)(k & 7);
      *(uint4*)(ws + WS_A_VW2 + (size_t)v*32768 + (size_t)k*256 + blk*16) = pack8(a, c);
    }
  } else if (b < 296){
    const int k2 = (b - 288) * 16 + (tid >> 4);
    const int h0 = (tid & 15) * 8;
    const float* gw = fgw + (size_t)k2 * 128;
    f32x4 a0 = {0,0,0,0}, a1 = {0,0,0,0};
    for (int k = 0; k < 128; ++k){
      float a = gw[k];
      f32x4 u = *(const f32x4*)(fw2 + k*128 + h0);
      f32x4 w = *(const f32x4*)(fw2 + k*128 + h0 + 4);
      #pragma unroll
      for (int e = 0; e < 4; ++e){ a0[e] = fmaf(a, u[e], a0[e]); a1[e] = fmaf(a, w[e], a1[e]); }
    }
    unsigned blk = (unsigned)(h0 >> 3) ^ (unsigned)(k2 & 7);
    *(uint4*)(ws + WS_A_WG1 + (size_t)k2*256 + blk*16) = pack8(a0, a1);
    if (b == 288 && tid < 128){
      const float* gr = fgw + (size_t)tid * 128;
      float s = fgb[tid];
      for (int k = 0; k < 128; ++k) s = fmaf(gr[k], fb2[k], s);
      ((float*)(ws + WS_BG1))[tid] = s;
    }
  } else if (b == 296){
    const int k = tid >> 1, hh = (tid & 1) * 64;
    const float* src = fw2 + (size_t)k * 128;
    #pragma unroll
    for (int i = 0; i < 8; ++i){
      int h0 = hh + i*8;
      f32x4 a = *(const f32x4*)(src + h0);
      f32x4 c = *(const f32x4*)(src + h0 + 4);
      unsigned blk = (unsigned)(h0 >> 3) ^ (unsigned)(k & 7);
      *(uint4*)(ws + WS_A_FW2 + (size_t)k*256 + blk*16) = pack8(a, c);
    }
  } else if (b == 297){
    const int k = tid >> 1, v0 = (tid & 1) * 16;
    #pragma unroll
    for (int i = 0; i < 2; ++i){
      f32x4 a  = *(const f32x4*)(fw1 + k*32 + v0 + i*8);
      f32x4 c  = *(const f32x4*)(fw1 + k*32 + v0 + i*8 + 4);
      *(uint4*)(ws + WS_A_FW1 + (size_t)k*64 + (size_t)v0*2 + i*16) = pack8(a, c);
      f32x4 a2 = *(const f32x4*)(fsw + k*32 + v0 + i*8);
      f32x4 c2 = *(const f32x4*)(fsw + k*32 + v0 + i*8 + 4);
      *(uint4*)(ws + WS_A_FSW + (size_t)k*64 + (size_t)v0*2 + i*16) = pack8(a2, c2);
    }
  }
}

// ---------------------------------------------------------------------------
// K1 (R12-verbatim): flattened GRN -> softmax weights (d_out[W_OFF..]).
// ---------------------------------------------------------------------------
__global__ __launch_bounds__(256) void k1_flat(
  const float* __restrict__ x,   const float* __restrict__ fb1,
  const float* __restrict__ fb2, const float* __restrict__ fsb,
  const float* __restrict__ flnw,const float* __restrict__ flnb,
  const unsigned char* __restrict__ ws, float* __restrict__ out)
{
  __shared__ __align__(16) unsigned char ldsW[65536];
  __shared__ __align__(16) unsigned char ldsH[4][4096];
  const int tid = threadIdx.x;
  const int wid = tid >> 6, lane = tid & 63;
  const int tl = lane & 15, q = lane >> 4;
  const int t0 = blockIdx.x * 64;
  const int tw = t0 + wid * 16 + tl;

  { // stage fw2' and wg1' into LDS
    const uint4* s1 = (const uint4*)(ws + WS_A_FW2);
    const uint4* s2 = (const uint4*)(ws + WS_A_WG1);
    uint4* d1 = (uint4*)ldsW;
    uint4* d2 = (uint4*)(ldsW + 32768);
    #pragma unroll
    for (int i = 0; i < 8; ++i){ d1[tid + i*256] = s1[tid + i*256]; d2[tid + i*256] = s2[tid + i*256]; }
  }
  bf16x8 xf;
  {
    f32x4 a = *(const f32x4*)(x + (size_t)tw*32 + q*8);
    f32x4 c = *(const f32x4*)(x + (size_t)tw*32 + q*8 + 4);
    #pragma unroll
    for (int e = 0; e < 4; ++e){ xf[e] = (bf16_t)a[e]; xf[e+4] = (bf16_t)c[e]; }
  }
  __syncthreads();

  const unsigned swzt = (unsigned)(tl & 7) << 4;
  #pragma unroll
  for (int mt = 0; mt < 8; ++mt){
    const int row = mt*16 + tl;
    uint4 araw = *(const uint4*)(ws + WS_A_FW1 + (size_t)row*64 + q*16);
    f32x4 acc = *(const f32x4*)(fb1 + mt*16 + q*4);
    acc = mfma16(asbf(araw), xf, acc);
    ushort4 hb;
    hb.x = f2bfu(eluf(acc[0])); hb.y = f2bfu(eluf(acc[1]));
    hb.z = f2bfu(eluf(acc[2])); hb.w = f2bfu(eluf(acc[3]));
    *(ushort4*)(ldsH[wid] + (unsigned)tl*256 + (((unsigned)(mt*32 + q*8)) ^ swzt)) = hb;
  }
  bf16x8 h1f[4];
  #pragma unroll
  for (int kb = 0; kb < 4; ++kb)
    h1f[kb] = asbf(*(const uint4*)(ldsH[wid] + (unsigned)tl*256 + (((unsigned)(kb*64 + q*16)) ^ swzt)));

  f32x4 wo[8];
  const float* bg1p = (const float*)(ws + WS_BG1);
  #pragma unroll
  for (int mt = 0; mt < 8; ++mt){
    const int row = mt*16 + tl;
    const uint4* aw = (const uint4*)(ldsW + (size_t)row*256);
    const uint4* ag = (const uint4*)(ldsW + 32768 + (size_t)row*256);
    const unsigned rsw = (unsigned)(row & 7);
    f32x4 h2 = *(const f32x4*)(fb2 + mt*16 + q*4);
    f32x4 gp = *(const f32x4*)(bg1p + mt*16 + q*4);
    #pragma unroll
    for (int kb = 0; kb < 4; ++kb){
      unsigned blk = (unsigned)(kb*4 + q) ^ rsw;
      h2 = mfma16(asbf(aw[blk]), h1f[kb], h2);
      gp = mfma16(asbf(ag[blk]), h1f[kb], gp);
    }
    uint4 asr = *(const uint4*)(ws + WS_A_FSW + (size_t)row*64 + q*16);
    f32x4 sk = *(const f32x4*)(fsb + mt*16 + q*4);
    sk = mfma16(asbf(asr), xf, sk);
    #pragma unroll
    for (int r = 0; r < 4; ++r){
      float g = sigmf(gp[r]);
      wo[mt][r] = sk[r] + g * (h2[r] - sk[r]);
    }
  }
  float sm = 0.f, sq = 0.f;
  #pragma unroll
  for (int mt = 0; mt < 8; ++mt)
  #pragma unroll
  for (int r = 0; r < 4; ++r){ float p = wo[mt][r]; sm += p; sq = fmaf(p, p, sq); }
  sm += __shfl_xor(sm, 16); sm += __shfl_xor(sm, 32);
  sq += __shfl_xor(sq, 16); sq += __shfl_xor(sq, 32);
  const float mean = sm * (1.f/128.f);
  const float var  = sq * (1.f/128.f) - mean*mean;
  const float rs   = __builtin_amdgcn_rsqf(var + 1e-5f);
  float wv[8];
  #pragma unroll
  for (int mt = 0; mt < 2; ++mt){
    f32x4 lw = *(const f32x4*)(flnw + mt*16 + q*4);
    f32x4 lb = *(const f32x4*)(flnb + mt*16 + q*4);
    #pragma unroll
    for (int r = 0; r < 4; ++r) wv[mt*4+r] = (wo[mt][r] - mean) * rs * lw[r] + lb[r];
  }
  float mx = wv[0];
  #pragma unroll
  for (int j = 1; j < 8; ++j) mx = fmaxf(mx, wv[j]);
  mx = fmaxf(mx, __shfl_xor(mx, 16)); mx = fmaxf(mx, __shfl_xor(mx, 32));
  float se = 0.f;
  #pragma unroll
  for (int j = 0; j < 8; ++j){ wv[j] = __expf(wv[j] - mx); se += wv[j]; }
  se += __shfl_xor(se, 16); se += __shfl_xor(se, 32);
  const float inv = __builtin_amdgcn_rcpf(se);
  #pragma unroll
  for (int mt = 0; mt < 2; ++mt)
  #pragma unroll
  for (int r = 0; r < 4; ++r)
    out[(size_t)W_OFF + (size_t)tw*32 + mt*16 + q*4 + r] = wv[mt*4+r] * inv;
}

// ---------------------------------------------------------------------------
// K2 (R15): R12 geometry (512 thr = 8 waves x 16 tokens, VPG=8, grid 512,
// 2 blocks/CU, 16 waves/CU). LDS-pipe relief: (1) A-slab double-buffered
// 2x32KB filled by async global_load_lds DMA (R13-proven skeleton; ds_writes
// eliminated; ONE barrier/vi); (2) G-fragments read directly from global
// (L2-resident, frag-major coalesced layout) — halves LDS read instructions.
// Math/operand mapping identical to R12 (absmax 0.0078).
// ---------------------------------------------------------------------------
__global__ __launch_bounds__(512, 2) void k2_main(
  const float* __restrict__ x,   const float* __restrict__ vw1,
  const float* __restrict__ vb1, const float* __restrict__ vb2,
  const float* __restrict__ vsw, const float* __restrict__ vsb,
  const float* __restrict__ vlnw,const float* __restrict__ vlnb,
  const unsigned char* __restrict__ ws, float* __restrict__ out,
  float* __restrict__ part, int nvg)
{
  __shared__ __align__(16) uint4 slabA[4096];  // 2 x 32KB A-slab double buffer
  const int tid = threadIdx.x;                 // 0..511
  const int wid = tid >> 6, lane = tid & 63;   // 8 waves
  const int tl = lane & 15, q = lane >> 4;
  const int bid = blockIdx.x;
  const int c   = bid & 127;                   // token chunk (128 x 128 tokens)
  const int g   = bid >> 7;                    // v-group
  const int VPG = 32 / nvg;
  const int vbase = g * VPG;
  const int t0 = ((c & 7) * 16 + (c >> 3)) * 128;   // XCD-clustered, bijective
  const int ta = t0 + wid * 16 + tl;
  const float* bg2p = (const float*)(ws + WS_BG2);
  float* __restrict__ dst = (g == nvg - 1) ? out : (part + (size_t)g * TOK * 128);

  auto stageA = [&](int buf, int v){
    const uint4* sa = (const uint4*)(ws + WS_A_VW2 + (size_t)v*32768) + tid;
    uint4* da = slabA + buf*2048 + tid;
    #pragma unroll
    for (int i = 0; i < 4; ++i)
      __builtin_amdgcn_global_load_lds(
        (const __attribute__((address_space(1))) void*)(sa + i*512),
        (__attribute__((address_space(3))) void*)(da + i*512), 16, 0, 0);
  };

  stageA(0, vbase);
  __syncthreads();            // drains DMA (vmcnt 0): buf0 ready

  f32x4 sel[8];
  #pragma unroll
  for (int mt = 0; mt < 8; ++mt) sel[mt] = (f32x4){0.f,0.f,0.f,0.f};

  int cur = 0;
  for (int vi = 0; vi < VPG; ++vi){
    const int v = vbase + vi;
    if (vi + 1 < VPG) stageA(cur ^ 1, v + 1);   // async prefetch under compute

    const float xv0 = x[(size_t)ta*32 + v];
    const float wt0 = out[(size_t)W_OFF + (size_t)ta*32 + v];

    // B-fragment: hv1 = elu(x*vw1 + vb1), elem e <-> h = kb*32 + 8q + e
    bf16x8 bf0[4];
    #pragma unroll
    for (int kb = 0; kb < 4; ++kb){
      const float* wp = vw1 + v*128 + kb*32 + q*8;
      const float* bp = vb1 + v*128 + kb*32 + q*8;
      f32x4 w0v = *(const f32x4*)wp, w1v = *(const f32x4*)(wp + 4);
      f32x4 b0v = *(const f32x4*)bp, b1v = *(const f32x4*)(bp + 4);
      bf16x8 f0;
      #pragma unroll
      for (int e = 0; e < 4; ++e){
        f0[e]   = (bf16_t)eluf(fmaf(xv0, w0v[e], b0v[e]));
        f0[e+4] = (bf16_t)eluf(fmaf(xv0, w1v[e], b1v[e]));
      }
      bf0[kb] = f0;
    }

    // fused GEMMs: A-frags from LDS buf[cur] (swizzled), G-frags from global
    // (frag-major coalesced, L2-resident)
    const uint4* sl = slabA + cur*2048;
    const uint4* gv = (const uint4*)(ws + WS_A_WG2 + (size_t)v*32768);
    f32x4 pre[8];
    #pragma unroll
    for (int mt = 0; mt < 8; ++mt){
      const int row = mt*16 + tl;
      const uint4* arow = sl + row*16;
      const unsigned rsw = (unsigned)(row & 7);
      f32x4 h0 = *(const f32x4*)(vb2 + v*128 + mt*16 + q*4);
      f32x4 g0 = *(const f32x4*)(bg2p + v*128 + mt*16 + q*4);
      bf16x8 gg[4];
      #pragma unroll
      for (int kb = 0; kb < 4; ++kb)
        gg[kb] = asbf(gv[(mt*4 + kb)*64 + q*16 + tl]);
      #pragma unroll
      for (int kb = 0; kb < 4; ++kb){
        const unsigned blk = (unsigned)(kb*4 + q) ^ rsw;
        h0 = mfma16(asbf(arow[blk]), bf0[kb], h0);
        g0 = mfma16(gg[kb], bf0[kb], g0);
      }
      f32x4 sw_ = *(const f32x4*)(vsw + v*128 + mt*16 + q*4);
      f32x4 sb_ = *(const f32x4*)(vsb + v*128 + mt*16 + q*4);
      #pragma unroll
      for (int r = 0; r < 4; ++r){
        float sk0 = fmaf(xv0, sw_[r], sb_[r]);
        pre[mt][r] = sk0 + sigmf(g0[r]) * (h0[r] - sk0);
      }
    }

    // LayerNorm + weighted select accumulation
    {
      float sm = 0.f, sq = 0.f;
      #pragma unroll
      for (int mt = 0; mt < 8; ++mt)
      #pragma unroll
      for (int r = 0; r < 4; ++r){ float p = pre[mt][r]; sm += p; sq = fmaf(p, p, sq); }
      sm += __shfl_xor(sm, 16); sm += __shfl_xor(sm, 32);
      sq += __shfl_xor(sq, 16); sq += __shfl_xor(sq, 32);
      const float mean = sm * (1.f/128.f);
      const float var  = sq * (1.f/128.f) - mean*mean;
      const float rsq  = __builtin_amdgcn_rsqf(var + 1e-5f);
      const float c1   = wt0 * rsq;
      #pragma unroll
      for (int mt = 0; mt < 8; ++mt){
        f32x4 lw = *(const f32x4*)(vlnw + v*128 + mt*16 + q*4);
        f32x4 lb = *(const f32x4*)(vlnb + v*128 + mt*16 + q*4);
        #pragma unroll
        for (int r = 0; r < 4; ++r)
          sel[mt][r] = fmaf((pre[mt][r] - mean) * lw[r], c1,
                            fmaf(wt0, lb[r], sel[mt][r]));
      }
    }

    __syncthreads();   // drains prefetch DMA; all waves done reading buf[cur]
    cur ^= 1;
  }

  // tail: direct stores (per mt: 4 q-lanes form one 64B segment per token)
  #pragma unroll
  for (int mt = 0; mt < 8; ++mt)
    *(f32x4*)(dst + (size_t)ta*128 + mt*16 + q*4) = sel[mt];
}

// ---------------------------------------------------------------------------
// K3: out += sum of partials (deterministic fixed order)
// ---------------------------------------------------------------------------
__global__ __launch_bounds__(256) void k3_reduce(float* __restrict__ out,
                                                 const float* __restrict__ part,
                                                 int nparts)
{
  const size_t idx = (size_t)blockIdx.x * 256 + threadIdx.x;
  f32x4 s = ((const f32x4*)out)[idx];
  for (int g = 0; g < nparts; ++g){
    f32x4 p = ((const f32x4*)part)[(size_t)g * TOK * 32 + idx];
    #pragma unroll
    for (int r = 0; r < 4; ++r) s[r] += p[r];
  }
  ((f32x4*)out)[idx] = s;
}

// ---------------------------------------------------------------------------
extern "C" void kernel_launch(void* const* d_in, const int* in_sizes, int n_in,
                              void* d_out, int out_size, void* d_ws, size_t ws_size,
                              hipStream_t stream)
{
  (void)in_sizes; (void)n_in; (void)out_size;
  const float* x    = (const float*)d_in[0];
  const float* fw1  = (const float*)d_in[1];
  const float* fb1  = (const float*)d_in[2];
  const float* fw2  = (const float*)d_in[3];
  const float* fb2  = (const float*)d_in[4];
  const float* fgw  = (const float*)d_in[5];
  const float* fgb  = (const float*)d_in[6];
  const float* fsw  = (const float*)d_in[7];
  const float* fsb  = (const float*)d_in[8];
  const float* flnw = (const float*)d_in[9];
  const float* flnb = (const float*)d_in[10];
  const float* vw1  = (const float*)d_in[11];
  const float* vb1  = (const float*)d_in[12];
  const float* vw2  = (const float*)d_in[13];
  const float* vb2  = (const float*)d_in[14];
  const float* vgw  = (const float*)d_in[15];
  const float* vgb  = (const float*)d_in[16];
  const float* vsw  = (const float*)d_in[17];
  const float* vsb  = (const float*)d_in[18];
  const float* vlnw = (const float*)d_in[19];
  const float* vlnb = (const float*)d_in[20];
  float* out = (float*)d_out;
  unsigned char* ws = (unsigned char*)d_ws;
  float* part = (float*)(ws + WS_PART);

  k0_prep<<<298, 256, 0, stream>>>(fw1, fw2, fgw, fgb, fb2, fsw, vw2, vgw, vgb, vb2, ws);
  k1_flat<<<256, 256, 0, stream>>>(x, fb1, fb2, fsb, flnw, flnb, ws, out);

  if (ws_size >= WS_PART + 3 * PART_SZ){
    // 4 v-groups of 8 vars: grid 512 -> 2 blocks/CU, 16 waves/CU
    k2_main<<<512, 512, 0, stream>>>(x, vw1, vb1, vb2, vsw, vsb, vlnw, vlnb,
                                     ws, out, part, 4);
    k3_reduce<<<2048, 256, 0, stream>>>(out, part, 3);
  } else if (ws_size >= WS_PART + PART_SZ){
    // 2 v-groups of 16 vars: grid 256
    k2_main<<<256, 512, 0, stream>>>(x, vw1, vb1, vb2, vsw, vsb, vlnw, vlnb,
                                     ws, out, part, 2);
    k3_reduce<<<2048, 256, 0, stream>>>(out, part, 1);
  } else {
    // fallback: single group, all 32 vars, grid 128 (correctness-safe)
    k2_main<<<128, 512, 0, stream>>>(x, vw1, vb1, vb2, vsw, vsb, vlnw, vlnb,
                                     ws, out, part, 1);
  }
}

// Round 16
// 140.448 us; speedup vs baseline: 1.2612x; 1.2187x over previous
//
#include <hip/hip_runtime.h>
#include <hip/hip_bf16.h>

typedef __bf16 bf16_t;
typedef __bf16 bf16x8 __attribute__((ext_vector_type(8)));
typedef float  f32x4  __attribute__((ext_vector_type(4)));

#define DEVFN static __device__ __forceinline__

constexpr int TOK   = 32 * 512;        // 16384 tokens
constexpr int W_OFF = TOK * 128;       // weights offset (floats) in d_out

// d_ws byte offsets
constexpr size_t WS_A_VW2 = 0;                                  // 1MB (bf16, XOR-swizzled rows)
constexpr size_t WS_A_WG2 = (size_t)1 << 20;                    // 1MB (bf16, XOR-swizzled rows)
constexpr size_t WS_BG2   = (size_t)2 << 20;                    // 16KB f32 [32][128]
constexpr size_t WS_A_FW2 = ((size_t)2 << 20) + (64u  << 10);   // 32KB (swizzled, k1)
constexpr size_t WS_A_WG1 = ((size_t)2 << 20) + (128u << 10);   // 32KB (swizzled, k1)
constexpr size_t WS_BG1   = ((size_t)2 << 20) + (192u << 10);   // 512B f32 [128]
constexpr size_t WS_A_FW1 = ((size_t)2 << 20) + (224u << 10);   // 8KB  (bf16, plain)
constexpr size_t WS_A_FSW = ((size_t)2 << 20) + (256u << 10);   // 8KB  (bf16, plain)
constexpr size_t WS_PART  = (size_t)3 << 20;                    // partial selected buffers
constexpr size_t PART_SZ  = (size_t)TOK * 128 * 4;              // 8.39MB each

DEVFN float eluf(float z)  { return z > 0.0f ? z : (__expf(z) - 1.0f); }
DEVFN float sigmf(float z) { return __builtin_amdgcn_rcpf(1.0f + __expf(-z)); }
DEVFN unsigned short f2bfu(float f){ bf16_t h = (bf16_t)f; return __builtin_bit_cast(unsigned short, h); }

DEVFN uint4 pack8(f32x4 a, f32x4 b){
  uint4 r;
  r.x = (unsigned)f2bfu(a[0]) | ((unsigned)f2bfu(a[1]) << 16);
  r.y = (unsigned)f2bfu(a[2]) | ((unsigned)f2bfu(a[3]) << 16);
  r.z = (unsigned)f2bfu(b[0]) | ((unsigned)f2bfu(b[1]) << 16);
  r.w = (unsigned)f2bfu(b[2]) | ((unsigned)f2bfu(b[3]) << 16);
  return r;
}
DEVFN f32x4 mfma16(bf16x8 a, bf16x8 b, f32x4 c){
  return __builtin_amdgcn_mfma_f32_16x16x32_bf16(a, b, c, 0, 0, 0);
}
DEVFN bf16x8 asbf(uint4 u){ return __builtin_bit_cast(bf16x8, u); }

// ---------------------------------------------------------------------------
// K0 (R12-verbatim): fused gate matrices (Wg2 = vgw·vw2, Wg1 = fgw·fw2, fused
// biases), bf16 packing, slab XOR-swizzle (frag f of row r stored at f^(r&7)).
// ---------------------------------------------------------------------------
__global__ void k0_prep(const float* __restrict__ fw1, const float* __restrict__ fw2,
                        const float* __restrict__ fgw, const float* __restrict__ fgb,
                        const float* __restrict__ fb2, const float* __restrict__ fsw,
                        const float* __restrict__ vw2, const float* __restrict__ vgw,
                        const float* __restrict__ vgb, const float* __restrict__ vb2,
                        unsigned char* __restrict__ ws)
{
  const int b = blockIdx.x, tid = threadIdx.x;
  if (b < 256){
    const int v  = b >> 3;
    const int k2 = (b & 7) * 16 + (tid >> 4);
    const int h0 = (tid & 15) * 8;
    const float* gw = vgw + ((size_t)v * 128 + k2) * 128;
    const float* w2 = vw2 + (size_t)v * 128 * 128;
    f32x4 a0 = {0,0,0,0}, a1 = {0,0,0,0};
    for (int k = 0; k < 128; ++k){
      float a = gw[k];
      f32x4 u = *(const f32x4*)(w2 + k*128 + h0);
      f32x4 w = *(const f32x4*)(w2 + k*128 + h0 + 4);
      #pragma unroll
      for (int e = 0; e < 4; ++e){ a0[e] = fmaf(a, u[e], a0[e]); a1[e] = fmaf(a, w[e], a1[e]); }
    }
    unsigned blk = (unsigned)(h0 >> 3) ^ (unsigned)(k2 & 7);
    *(uint4*)(ws + WS_A_WG2 + (size_t)v*32768 + (size_t)k2*256 + blk*16) = pack8(a0, a1);
    if ((b & 7) == 0 && tid < 128){
      const float* gr = vgw + ((size_t)v*128 + tid) * 128;
      const float* vb = vb2 + v*128;
      float s = vgb[v*128 + tid];
      for (int k = 0; k < 128; ++k) s = fmaf(gr[k], vb[k], s);
      ((float*)(ws + WS_BG2))[v*128 + tid] = s;
    }
  } else if (b < 288){
    const int v = b - 256;
    const int k = tid >> 1, hh = (tid & 1) * 64;
    const float* src = vw2 + ((size_t)v*128 + k) * 128;
    #pragma unroll
    for (int i = 0; i < 8; ++i){
      int h0 = hh + i*8;
      f32x4 a = *(const f32x4*)(src + h0);
      f32x4 c = *(const f32x4*)(src + h0 + 4);
      unsigned blk = (unsigned)(h0 >> 3) ^ (unsigned)(k & 7);
      *(uint4*)(ws + WS_A_VW2 + (size_t)v*32768 + (size_t)k*256 + blk*16) = pack8(a, c);
    }
  } else if (b < 296){
    const int k2 = (b - 288) * 16 + (tid >> 4);
    const int h0 = (tid & 15) * 8;
    const float* gw = fgw + (size_t)k2 * 128;
    f32x4 a0 = {0,0,0,0}, a1 = {0,0,0,0};
    for (int k = 0; k < 128; ++k){
      float a = gw[k];
      f32x4 u = *(const f32x4*)(fw2 + k*128 + h0);
      f32x4 w = *(const f32x4*)(fw2 + k*128 + h0 + 4);
      #pragma unroll
      for (int e = 0; e < 4; ++e){ a0[e] = fmaf(a, u[e], a0[e]); a1[e] = fmaf(a, w[e], a1[e]); }
    }
    unsigned blk = (unsigned)(h0 >> 3) ^ (unsigned)(k2 & 7);
    *(uint4*)(ws + WS_A_WG1 + (size_t)k2*256 + blk*16) = pack8(a0, a1);
    if (b == 288 && tid < 128){
      const float* gr = fgw + (size_t)tid * 128;
      float s = fgb[tid];
      for (int k = 0; k < 128; ++k) s = fmaf(gr[k], fb2[k], s);
      ((float*)(ws + WS_BG1))[tid] = s;
    }
  } else if (b == 296){
    const int k = tid >> 1, hh = (tid & 1) * 64;
    const float* src = fw2 + (size_t)k * 128;
    #pragma unroll
    for (int i = 0; i < 8; ++i){
      int h0 = hh + i*8;
      f32x4 a = *(const f32x4*)(src + h0);
      f32x4 c = *(const f32x4*)(src + h0 + 4);
      unsigned blk = (unsigned)(h0 >> 3) ^ (unsigned)(k & 7);
      *(uint4*)(ws + WS_A_FW2 + (size_t)k*256 + blk*16) = pack8(a, c);
    }
  } else if (b == 297){
    const int k = tid >> 1, v0 = (tid & 1) * 16;
    #pragma unroll
    for (int i = 0; i < 2; ++i){
      f32x4 a  = *(const f32x4*)(fw1 + k*32 + v0 + i*8);
      f32x4 c  = *(const f32x4*)(fw1 + k*32 + v0 + i*8 + 4);
      *(uint4*)(ws + WS_A_FW1 + (size_t)k*64 + (size_t)v0*2 + i*16) = pack8(a, c);
      f32x4 a2 = *(const f32x4*)(fsw + k*32 + v0 + i*8);
      f32x4 c2 = *(const f32x4*)(fsw + k*32 + v0 + i*8 + 4);
      *(uint4*)(ws + WS_A_FSW + (size_t)k*64 + (size_t)v0*2 + i*16) = pack8(a2, c2);
    }
  }
}

// ---------------------------------------------------------------------------
// K1 (R12-verbatim): flattened GRN -> softmax weights (d_out[W_OFF..]).
// ---------------------------------------------------------------------------
__global__ __launch_bounds__(256) void k1_flat(
  const float* __restrict__ x,   const float* __restrict__ fb1,
  const float* __restrict__ fb2, const float* __restrict__ fsb,
  const float* __restrict__ flnw,const float* __restrict__ flnb,
  const unsigned char* __restrict__ ws, float* __restrict__ out)
{
  __shared__ __align__(16) unsigned char ldsW[65536];
  __shared__ __align__(16) unsigned char ldsH[4][4096];
  const int tid = threadIdx.x;
  const int wid = tid >> 6, lane = tid & 63;
  const int tl = lane & 15, q = lane >> 4;
  const int t0 = blockIdx.x * 64;
  const int tw = t0 + wid * 16 + tl;

  { // stage fw2' and wg1' into LDS
    const uint4* s1 = (const uint4*)(ws + WS_A_FW2);
    const uint4* s2 = (const uint4*)(ws + WS_A_WG1);
    uint4* d1 = (uint4*)ldsW;
    uint4* d2 = (uint4*)(ldsW + 32768);
    #pragma unroll
    for (int i = 0; i < 8; ++i){ d1[tid + i*256] = s1[tid + i*256]; d2[tid + i*256] = s2[tid + i*256]; }
  }
  bf16x8 xf;
  {
    f32x4 a = *(const f32x4*)(x + (size_t)tw*32 + q*8);
    f32x4 c = *(const f32x4*)(x + (size_t)tw*32 + q*8 + 4);
    #pragma unroll
    for (int e = 0; e < 4; ++e){ xf[e] = (bf16_t)a[e]; xf[e+4] = (bf16_t)c[e]; }
  }
  __syncthreads();

  const unsigned swzt = (unsigned)(tl & 7) << 4;
  #pragma unroll
  for (int mt = 0; mt < 8; ++mt){
    const int row = mt*16 + tl;
    uint4 araw = *(const uint4*)(ws + WS_A_FW1 + (size_t)row*64 + q*16);
    f32x4 acc = *(const f32x4*)(fb1 + mt*16 + q*4);
    acc = mfma16(asbf(araw), xf, acc);
    ushort4 hb;
    hb.x = f2bfu(eluf(acc[0])); hb.y = f2bfu(eluf(acc[1]));
    hb.z = f2bfu(eluf(acc[2])); hb.w = f2bfu(eluf(acc[3]));
    *(ushort4*)(ldsH[wid] + (unsigned)tl*256 + (((unsigned)(mt*32 + q*8)) ^ swzt)) = hb;
  }
  bf16x8 h1f[4];
  #pragma unroll
  for (int kb = 0; kb < 4; ++kb)
    h1f[kb] = asbf(*(const uint4*)(ldsH[wid] + (unsigned)tl*256 + (((unsigned)(kb*64 + q*16)) ^ swzt)));

  f32x4 wo[8];
  const float* bg1p = (const float*)(ws + WS_BG1);
  #pragma unroll
  for (int mt = 0; mt < 8; ++mt){
    const int row = mt*16 + tl;
    const uint4* aw = (const uint4*)(ldsW + (size_t)row*256);
    const uint4* ag = (const uint4*)(ldsW + 32768 + (size_t)row*256);
    const unsigned rsw = (unsigned)(row & 7);
    f32x4 h2 = *(const f32x4*)(fb2 + mt*16 + q*4);
    f32x4 gp = *(const f32x4*)(bg1p + mt*16 + q*4);
    #pragma unroll
    for (int kb = 0; kb < 4; ++kb){
      unsigned blk = (unsigned)(kb*4 + q) ^ rsw;
      h2 = mfma16(asbf(aw[blk]), h1f[kb], h2);
      gp = mfma16(asbf(ag[blk]), h1f[kb], gp);
    }
    uint4 asr = *(const uint4*)(ws + WS_A_FSW + (size_t)row*64 + q*16);
    f32x4 sk = *(const f32x4*)(fsb + mt*16 + q*4);
    sk = mfma16(asbf(asr), xf, sk);
    #pragma unroll
    for (int r = 0; r < 4; ++r){
      float g = sigmf(gp[r]);
      wo[mt][r] = sk[r] + g * (h2[r] - sk[r]);
    }
  }
  float sm = 0.f, sq = 0.f;
  #pragma unroll
  for (int mt = 0; mt < 8; ++mt)
  #pragma unroll
  for (int r = 0; r < 4; ++r){ float p = wo[mt][r]; sm += p; sq = fmaf(p, p, sq); }
  sm += __shfl_xor(sm, 16); sm += __shfl_xor(sm, 32);
  sq += __shfl_xor(sq, 16); sq += __shfl_xor(sq, 32);
  const float mean = sm * (1.f/128.f);
  const float var  = sq * (1.f/128.f) - mean*mean;
  const float rs   = __builtin_amdgcn_rsqf(var + 1e-5f);
  float wv[8];
  #pragma unroll
  for (int mt = 0; mt < 2; ++mt){
    f32x4 lw = *(const f32x4*)(flnw + mt*16 + q*4);
    f32x4 lb = *(const f32x4*)(flnb + mt*16 + q*4);
    #pragma unroll
    for (int r = 0; r < 4; ++r) wv[mt*4+r] = (wo[mt][r] - mean) * rs * lw[r] + lb[r];
  }
  float mx = wv[0];
  #pragma unroll
  for (int j = 1; j < 8; ++j) mx = fmaxf(mx, wv[j]);
  mx = fmaxf(mx, __shfl_xor(mx, 16)); mx = fmaxf(mx, __shfl_xor(mx, 32));
  float se = 0.f;
  #pragma unroll
  for (int j = 0; j < 8; ++j){ wv[j] = __expf(wv[j] - mx); se += wv[j]; }
  se += __shfl_xor(se, 16); se += __shfl_xor(se, 32);
  const float inv = __builtin_amdgcn_rcpf(se);
  #pragma unroll
  for (int mt = 0; mt < 2; ++mt)
  #pragma unroll
  for (int r = 0; r < 4; ++r)
    out[(size_t)W_OFF + (size_t)tw*32 + mt*16 + q*4 + r] = wv[mt*4+r] * inv;
}

// ---------------------------------------------------------------------------
// K2 (R16 = R12 + DMA staging): 512-thread blocks = 8 waves x 16 tokens;
// VPG=8; grid 512 -> 2 blocks/CU -> 16 waves/CU. ONLY delta vs R12: the slab
// staging uses __builtin_amdgcn_global_load_lds (validated in R13/R15) —
// removes 8 ds_writes/thread/vi from the LDS pipe and the VGPR round-trip.
// Barrier structure, math, swizzle, tail: R12-verbatim.
// ---------------------------------------------------------------------------
__global__ __launch_bounds__(512, 2) void k2_main(
  const float* __restrict__ x,   const float* __restrict__ vw1,
  const float* __restrict__ vb1, const float* __restrict__ vb2,
  const float* __restrict__ vsw, const float* __restrict__ vsb,
  const float* __restrict__ vlnw,const float* __restrict__ vlnb,
  const unsigned char* __restrict__ ws, float* __restrict__ out,
  float* __restrict__ part, int nvg)
{
  __shared__ __align__(16) uint4 slab[4096];   // [A 2048 | G 2048] = 64KB
  const int tid = threadIdx.x;                 // 0..511
  const int wid = tid >> 6, lane = tid & 63;   // 8 waves
  const int tl = lane & 15, q = lane >> 4;
  const int bid = blockIdx.x;
  const int c   = bid & 127;                   // token chunk (128 x 128 tokens)
  const int g   = bid >> 7;                    // v-group
  const int VPG = 32 / nvg;
  const int vbase = g * VPG;
  const int t0 = ((c & 7) * 16 + (c >> 3)) * 128;   // XCD-clustered, bijective
  const int ta = t0 + wid * 16 + tl;
  const float* bg2p = (const float*)(ws + WS_BG2);
  float* __restrict__ dst = (g == nvg - 1) ? out : (part + (size_t)g * TOK * 128);

  auto stage = [&](int v){
    const uint4* sa = (const uint4*)(ws + WS_A_VW2 + (size_t)v*32768) + tid;
    const uint4* sg = (const uint4*)(ws + WS_A_WG2 + (size_t)v*32768) + tid;
    uint4* da = slab + tid;
    uint4* dg = slab + 2048 + tid;
    #pragma unroll
    for (int i = 0; i < 4; ++i)
      __builtin_amdgcn_global_load_lds(
        (const __attribute__((address_space(1))) void*)(sa + i*512),
        (__attribute__((address_space(3))) void*)(da + i*512), 16, 0, 0);
    #pragma unroll
    for (int i = 0; i < 4; ++i)
      __builtin_amdgcn_global_load_lds(
        (const __attribute__((address_space(1))) void*)(sg + i*512),
        (__attribute__((address_space(3))) void*)(dg + i*512), 16, 0, 0);
  };

  stage(vbase);
  __syncthreads();           // vmcnt(0) drain completes DMA; slab ready

  f32x4 sel[8];
  #pragma unroll
  for (int mt = 0; mt < 8; ++mt) sel[mt] = (f32x4){0.f,0.f,0.f,0.f};

  for (int vi = 0; vi < VPG; ++vi){
    const int v = vbase + vi;
    const float xv0 = x[(size_t)ta*32 + v];
    const float wt0 = out[(size_t)W_OFF + (size_t)ta*32 + v];

    // B-fragment: hv1 = elu(x*vw1 + vb1), elem e <-> h = kb*32 + 8q + e
    bf16x8 bf0[4];
    #pragma unroll
    for (int kb = 0; kb < 4; ++kb){
      const float* wp = vw1 + v*128 + kb*32 + q*8;
      const float* bp = vb1 + v*128 + kb*32 + q*8;
      f32x4 w0v = *(const f32x4*)wp, w1v = *(const f32x4*)(wp + 4);
      f32x4 b0v = *(const f32x4*)bp, b1v = *(const f32x4*)(bp + 4);
      bf16x8 f0;
      #pragma unroll
      for (int e = 0; e < 4; ++e){
        f0[e]   = (bf16_t)eluf(fmaf(xv0, w0v[e], b0v[e]));
        f0[e+4] = (bf16_t)eluf(fmaf(xv0, w1v[e], b1v[e]));
      }
      bf0[kb] = f0;
    }

    // fused GEMMs from the shared LDS slab (swizzled frag reads)
    f32x4 pre[8];
    #pragma unroll
    for (int mt = 0; mt < 8; ++mt){
      const int row = mt*16 + tl;
      const uint4* arow = slab + row*16;
      const uint4* grow = slab + 2048 + row*16;
      const unsigned rsw = (unsigned)(row & 7);
      f32x4 h0 = *(const f32x4*)(vb2 + v*128 + mt*16 + q*4);
      f32x4 g0 = *(const f32x4*)(bg2p + v*128 + mt*16 + q*4);
      #pragma unroll
      for (int kb = 0; kb < 4; ++kb){
        const unsigned blk = (unsigned)(kb*4 + q) ^ rsw;
        h0 = mfma16(asbf(arow[blk]), bf0[kb], h0);
        g0 = mfma16(asbf(grow[blk]), bf0[kb], g0);
      }
      f32x4 sw_ = *(const f32x4*)(vsw + v*128 + mt*16 + q*4);
      f32x4 sb_ = *(const f32x4*)(vsb + v*128 + mt*16 + q*4);
      #pragma unroll
      for (int r = 0; r < 4; ++r){
        float sk0 = fmaf(xv0, sw_[r], sb_[r]);
        pre[mt][r] = sk0 + sigmf(g0[r]) * (h0[r] - sk0);
      }
    }

    // LayerNorm + weighted select accumulation
    {
      float sm = 0.f, sq = 0.f;
      #pragma unroll
      for (int mt = 0; mt < 8; ++mt)
      #pragma unroll
      for (int r = 0; r < 4; ++r){ float p = pre[mt][r]; sm += p; sq = fmaf(p, p, sq); }
      sm += __shfl_xor(sm, 16); sm += __shfl_xor(sm, 32);
      sq += __shfl_xor(sq, 16); sq += __shfl_xor(sq, 32);
      const float mean = sm * (1.f/128.f);
      const float var  = sq * (1.f/128.f) - mean*mean;
      const float rsq  = __builtin_amdgcn_rsqf(var + 1e-5f);
      const float c1   = wt0 * rsq;
      #pragma unroll
      for (int mt = 0; mt < 8; ++mt){
        f32x4 lw = *(const f32x4*)(vlnw + v*128 + mt*16 + q*4);
        f32x4 lb = *(const f32x4*)(vlnb + v*128 + mt*16 + q*4);
        #pragma unroll
        for (int r = 0; r < 4; ++r)
          sel[mt][r] = fmaf((pre[mt][r] - mean) * lw[r], c1,
                            fmaf(wt0, lb[r], sel[mt][r]));
      }
    }

    __syncthreads();                       // all waves done READING slab(v)
    if (vi + 1 < VPG){                     // DMA restage slab(v+1), then barrier
      stage(v + 1);
      __syncthreads();                     // vmcnt(0) drain: slab(v+1) ready
    }
  }

  // tail: direct stores (per mt: 4 q-lanes form one 64B segment per token)
  #pragma unroll
  for (int mt = 0; mt < 8; ++mt)
    *(f32x4*)(dst + (size_t)ta*128 + mt*16 + q*4) = sel[mt];
}

// ---------------------------------------------------------------------------
// K3: out += sum of partials (deterministic fixed order)
// ---------------------------------------------------------------------------
__global__ __launch_bounds__(256) void k3_reduce(float* __restrict__ out,
                                                 const float* __restrict__ part,
                                                 int nparts)
{
  const size_t idx = (size_t)blockIdx.x * 256 + threadIdx.x;
  f32x4 s = ((const f32x4*)out)[idx];
  for (int g = 0; g < nparts; ++g){
    f32x4 p = ((const f32x4*)part)[(size_t)g * TOK * 32 + idx];
    #pragma unroll
    for (int r = 0; r < 4; ++r) s[r] += p[r];
  }
  ((f32x4*)out)[idx] = s;
}

// ---------------------------------------------------------------------------
extern "C" void kernel_launch(void* const* d_in, const int* in_sizes, int n_in,
                              void* d_out, int out_size, void* d_ws, size_t ws_size,
                              hipStream_t stream)
{
  (void)in_sizes; (void)n_in; (void)out_size;
  const float* x    = (const float*)d_in[0];
  const float* fw1  = (const float*)d_in[1];
  const float* fb1  = (const float*)d_in[2];
  const float* fw2  = (const float*)d_in[3];
  const float* fb2  = (const float*)d_in[4];
  const float* fgw  = (const float*)d_in[5];
  const float* fgb  = (const float*)d_in[6];
  const float* fsw  = (const float*)d_in[7];
  const float* fsb  = (const float*)d_in[8];
  const float* flnw = (const float*)d_in[9];
  const float* flnb = (const float*)d_in[10];
  const float* vw1  = (const float*)d_in[11];
  const float* vb1  = (const float*)d_in[12];
  const float* vw2  = (const float*)d_in[13];
  const float* vb2  = (const float*)d_in[14];
  const float* vgw  = (const float*)d_in[15];
  const float* vgb  = (const float*)d_in[16];
  const float* vsw  = (const float*)d_in[17];
  const float* vsb  = (const float*)d_in[18];
  const float* vlnw = (const float*)d_in[19];
  const float* vlnb = (const float*)d_in[20];
  float* out = (float*)d_out;
  unsigned char* ws = (unsigned char*)d_ws;
  float* part = (float*)(ws + WS_PART);

  k0_prep<<<298, 256, 0, stream>>>(fw1, fw2, fgw, fgb, fb2, fsw, vw2, vgw, vgb, vb2, ws);
  k1_flat<<<256, 256, 0, stream>>>(x, fb1, fb2, fsb, flnw, flnb, ws, out);

  if (ws_size >= WS_PART + 3 * PART_SZ){
    // 4 v-groups of 8 vars: grid 512 -> 2 blocks/CU, 16 waves/CU
    k2_main<<<512, 512, 0, stream>>>(x, vw1, vb1, vb2, vsw, vsb, vlnw, vlnb,
                                     ws, out, part, 4);
    k3_reduce<<<2048, 256, 0, stream>>>(out, part, 3);
  } else if (ws_size >= WS_PART + PART_SZ){
    // 2 v-groups of 16 vars: grid 256
    k2_main<<<256, 512, 0, stream>>>(x, vw1, vb1, vb2, vsw, vsb, vlnw, vlnb,
                                     ws, out, part, 2);
    k3_reduce<<<2048, 256, 0, stream>>>(out, part, 1);
  } else {
    // fallback: single group, all 32 vars, grid 128 (correctness-safe)
    k2_main<<<128, 512, 0, stream>>>(x, vw1, vb1, vb2, vsw, vsb, vlnw, vlnb,
                                     ws, out, part, 1);
  }
}